// Round 5
// baseline (442.535 us; speedup 1.0000x reference)
//
#include <hip/hip_runtime.h>
#include <hip/hip_bf16.h>
#include <math.h>
#include <stdint.h>

#define B_ 8
#define T_ 128
#define U1_ 33
#define D_ 512
#define V_ 4096
#define M_ (B_*T_*U1_)   /* 33792 */

#define BLANK_ 0
#define PAD_ 1

#define TM 128           /* block M tile */
#define TN 128           /* block N tile */
#define BKB 128          /* K step in fp8 bytes (= MFMA K) */
#define NK (D_/BKB)      /* 4 */
#define GN (V_/TN)       /* 32 n-tiles */

typedef __attribute__((ext_vector_type(4))) float fvec4;
typedef __attribute__((ext_vector_type(8))) int   i8v;    // 32 fp8 = 8 VGPRs
typedef __attribute__((ext_vector_type(4))) int   i4v;

// E8M0 block scales: A x1 (2^0=bias127), B x2^-6 (121) to undo the x64 pre-scale
#define SCALE_A 0x7F7F7F7Fu
#define SCALE_B 0x79797979u

__device__ __forceinline__ void load_lds16(const uint8_t* g, uint8_t* l) {
    __builtin_amdgcn_global_load_lds(
        (const __attribute__((address_space(1))) unsigned int*)g,
        (__attribute__((address_space(3))) unsigned int*)l, 16, 0, 0);
}

__device__ __forceinline__ unsigned pack4_fp8(fvec4 v) {
    int r = __builtin_amdgcn_cvt_pk_fp8_f32(v.x, v.y, 0, false);
    r = __builtin_amdgcn_cvt_pk_fp8_f32(v.z, v.w, r, true);
    return (unsigned)r;
}

// ---------------------------------------------------------------------------
// Kernel 0: fp32 -> fp8 e4m3 convert; w is pre-scaled by 64 (undone by SCALE_B).
// Fused: blocks 0-31 also compute the column-sum of W + bias_sum into wsum
// (sum_v z[r,v] = x_row . wsum + bias_sum is linear -> no sum(z) reduction
// anywhere in the GEMM).
// ---------------------------------------------------------------------------
__global__ void convert_kernel(const float* __restrict__ x, const float* __restrict__ w,
                               const float* __restrict__ bias,
                               uint8_t* __restrict__ xf8, uint8_t* __restrict__ wf8,
                               float* __restrict__ wsum)
{
    int i = blockIdx.x * 256 + threadIdx.x;
    int stride = gridDim.x * 256;
    const int nx = (M_ * D_) / 16;   // 1081344 16B-groups
    const int nw = (V_ * D_) / 16;   // 131072
    for (int j = i; j < nx; j += stride) {
        const fvec4* p = (const fvec4*)x + (size_t)j * 4;
        uint4 o = { pack4_fp8(p[0]), pack4_fp8(p[1]), pack4_fp8(p[2]), pack4_fp8(p[3]) };
        ((uint4*)xf8)[j] = o;
    }
    for (int j = i; j < nw; j += stride) {
        const fvec4* p = (const fvec4*)w + (size_t)j * 4;
        fvec4 v0 = p[0]*64.0f, v1 = p[1]*64.0f, v2 = p[2]*64.0f, v3 = p[3]*64.0f;
        uint4 o = { pack4_fp8(v0), pack4_fp8(v1), pack4_fp8(v2), pack4_fp8(v3) };
        ((uint4*)wf8)[j] = o;
    }
    // fused wsum: 32 blocks x 256 threads
    if (blockIdx.x < 32) {
        const int t = threadIdx.x;
        const int v0 = blockIdx.x * 128;
        float s0 = 0.0f, s1 = 0.0f;
        for (int v = 0; v < 128; v++) {
            s0 += w[(size_t)(v0 + v) * D_ + t];
            s1 += w[(size_t)(v0 + v) * D_ + t + 256];
        }
        atomicAdd(&wsum[t], s0);
        atomicAdd(&wsum[t + 256], s1);
        if (blockIdx.x == 0) {
            float bsum = 0.0f;
            for (int v = t; v < V_; v += 256) bsum += bias[v];
            atomicAdd(&wsum[D_], bsum);   // bias_sum in slot 512
        }
    }
}

// ---------------------------------------------------------------------------
// Kernel 1: MX-fp8 GEMM (x @ W^T + bias), 16x16x128 f8f6f4 scaled MFMA.
// K-loop: round-0 verbatim 2-barrier structure (stage -> frag reads -> MFMA
// -> __syncthreads(); VGPR=96, no spill). Counted-vmcnt/raw-barrier variants
// spill on this compiler (rounds 1-3) — lever closed.
// XCD-chunked bijective swizzle (round-4 verified: FETCH 86->16.8 MB): XCD k
// owns m-tiles [33k, 33k+33), n-tile fastest -> working set L2-resident.
// Epilogue: per-row sum(exp(z)) accumulated in LDS, then ONE global atomic
// per row per block into se[M_] (replaces the partial_e array + combine
// kernel; 32-way contention per address, negligible over 174us).
// grid (264, 32), block 256 (2x2 waves of 64x64).
// ---------------------------------------------------------------------------
__global__ __launch_bounds__(256, 2)
void gemm_fused(const uint8_t* __restrict__ xf8, const uint8_t* __restrict__ wf8,
                const float* __restrict__ bias, const int* __restrict__ targets,
                float* __restrict__ se_glob,
                float* __restrict__ blank_z, float* __restrict__ emit_z)
{
    __shared__ __align__(16) uint8_t As[2][TM * BKB];   // 16 KB x2
    __shared__ __align__(16) uint8_t Bs[2][TN * BKB];   // 16 KB x2
    __shared__ float ps[TM];
    __shared__ int tgt_s[TM];

    const int tid  = threadIdx.x;
    const int lane = tid & 63;
    const int wid  = tid >> 6;

    // XCD-chunked swizzle (8448 blocks, 8448%8==0 -> bijective):
    // fid%8 = XCD; XCD k gets m-tiles [33k, 33k+33), n-tile fastest.
    const int fid = blockIdx.y * gridDim.x + blockIdx.x;
    const int xcd = fid & 7;
    const int idx = fid >> 3;            // 0..1055
    const int mt  = xcd * 33 + (idx >> 5);
    const int nt  = idx & 31;
    const int m0  = mt * TM;
    const int n0  = nt * TN;

    // staging: lane i -> LDS (row = wid*32 + j*8 + (i>>3), chunk = i&7);
    // global src chunk is XOR-swizzled by row&7
    const int srow = wid * 32 + (lane >> 3);
    const int schk = (lane & 7) ^ ((lane >> 3) & 7);
    const uint8_t* agp = xf8 + (size_t)(m0 + srow) * D_ + schk * 16;
    const uint8_t* bgp = wf8 + (size_t)(n0 + srow) * D_ + schk * 16;

    fvec4 acc[4][4];
#pragma unroll
    for (int i = 0; i < 4; i++)
#pragma unroll
        for (int j = 0; j < 4; j++) acc[i][j] = (fvec4)0.0f;

    const int wrow = (wid >> 1) * 64;
    const int wcol = (wid & 1) * 64;
    const int m15  = lane & 15;
    const int quad = lane >> 4;

    auto stage = [&](int buf, int ks) {
        const uint8_t* ag = agp + ks * BKB;
        const uint8_t* bg = bgp + ks * BKB;
#pragma unroll
        for (int j = 0; j < 4; j++) {
            load_lds16(ag + j * 8 * D_, &As[buf][(wid * 32 + j * 8) * BKB]);
            load_lds16(bg + j * 8 * D_, &Bs[buf][(wid * 32 + j * 8) * BKB]);
        }
    };

    stage(0, 0);
    if (tid < TM) {   // init before the first barrier: covered by it, no extra sync
        ps[tid] = 0.0f;
        int row = m0 + tid;
        int u = row % U1_;
        int b = row / (T_ * U1_);
        tgt_s[tid] = (u < U1_ - 1) ? targets[b * (U1_ - 1) + u] : -1;
    }
    __syncthreads();

    const int e   = m15 & 7;               // row&7 for all frag rows
    const int c0b = (((quad << 1) ^ e) << 4);   // first 16B chunk byte offset

    for (int ks = 0; ks < NK; ks++) {
        const int cur = ks & 1;
        if (ks + 1 < NK) stage(cur ^ 1, ks + 1);

        i8v fa[4], fb[4];
#pragma unroll
        for (int mi = 0; mi < 4; mi++) {
            int base = (wrow + mi * 16 + m15) << 7;   // row*128
            union { i4v h[2]; i8v w; } u;
            u.h[0] = *(const i4v*)&As[cur][base + c0b];
            u.h[1] = *(const i4v*)&As[cur][base + (c0b ^ 16)];
            fa[mi] = u.w;
        }
#pragma unroll
        for (int ni = 0; ni < 4; ni++) {
            int base = (wcol + ni * 16 + m15) << 7;
            union { i4v h[2]; i8v w; } u;
            u.h[0] = *(const i4v*)&Bs[cur][base + c0b];
            u.h[1] = *(const i4v*)&Bs[cur][base + (c0b ^ 16)];
            fb[ni] = u.w;
        }
#pragma unroll
        for (int mi = 0; mi < 4; mi++)
#pragma unroll
            for (int ni = 0; ni < 4; ni++)
                acc[mi][ni] = __builtin_amdgcn_mfma_scale_f32_16x16x128_f8f6f4(
                                  fa[mi], fb[ni], acc[mi][ni],
                                  0, 0,                 // fmtA=fp8, fmtB=fp8
                                  0, SCALE_A, 0, SCALE_B);
        __syncthreads();
    }

    // ---- epilogue ----
    float bv[4];
#pragma unroll
    for (int ni = 0; ni < 4; ni++) bv[ni] = bias[n0 + wcol + ni * 16 + m15];

    const bool blank_lane = (nt == 0) && (wcol == 0) && (m15 == 0);

#pragma unroll
    for (int mi = 0; mi < 4; mi++) {
#pragma unroll
        for (int r = 0; r < 4; r++) {
            const int irow = wrow + mi * 16 + quad * 4 + r;
            float se = 0.0f;
#pragma unroll
            for (int ni = 0; ni < 4; ni++) {
                float z = acc[mi][ni][r] + bv[ni];
                se += __expf(z);
                int c = n0 + wcol + ni * 16 + m15;
                if (tgt_s[irow] == c) emit_z[m0 + irow] = z;
            }
            if (blank_lane) blank_z[m0 + irow] = acc[mi][0][r] + bv[0];
            se += __shfl_xor(se, 1, 64);
            se += __shfl_xor(se, 2, 64);
            se += __shfl_xor(se, 4, 64);
            se += __shfl_xor(se, 8, 64);
            if (m15 == 0) atomicAdd(&ps[irow], se);
        }
    }
    __syncthreads();
    if (tid < TM) {
        atomicAdd(&se_glob[m0 + tid], ps[tid]);   // 1 global atomic / row / block
    }
}

// ---------------------------------------------------------------------------
// Kernel 2: RNN-T forward DP, one block per utterance, lse computed inline
// (l = log(se[g]) — O(1) per element now that se is a single accumulator).
// Wave 0 runs the DP; threads 64.. run the label-smoothed CE rows (t = sl-1)
// concurrently, hidden under the serial DP.
// ---------------------------------------------------------------------------
__global__ __launch_bounds__(256)
void dp_kernel(const float* __restrict__ se_glob,
               const float* __restrict__ blank_z, const float* __restrict__ emit_z,
               const int* __restrict__ targets,
               const int* __restrict__ src_lengths, const int* __restrict__ tgt_lengths,
               const float* __restrict__ x, const float* __restrict__ wsum,
               float* __restrict__ out)
{
    __shared__ float blp[T_ * U1_];
    __shared__ float elp[T_ * U1_];
    const int tid = threadIdx.x;
    const int b = blockIdx.x;
    const int sl = src_lengths[b], tl = tgt_lengths[b];

    for (int i = tid; i < T_ * U1_; i += 256) {
        int g = b * T_ * U1_ + i;
        float l = __logf(se_glob[g]);
        blp[i] = blank_z[g] - l;
        elp[i] = emit_z[g] - l;
    }
    __syncthreads();

    if (tid >= 64) {
        // CE rows: u in [0, U1-1), t = sl-1 — concurrent with the DP wave
        if (tid < 64 + (U1_ - 1)) {
            int u = tid - 64;
            int tgt = targets[b * (U1_ - 1) + u];
            if (tgt != PAD_) {
                int i = (sl - 1) * U1_ + u;
                int g = b * T_ * U1_ + i;
                float l = __logf(se_glob[g]);
                // sum_v z = x_row . wsum + bias_sum  (exact fp32)
                float sz = wsum[D_];
                const fvec4* xr = (const fvec4*)(x + (size_t)g * D_);
                const fvec4* ws = (const fvec4*)wsum;
#pragma unroll 4
                for (int d = 0; d < D_ / 4; d++) {
                    fvec4 a = xr[d], wv = ws[d];
                    sz += a.x * wv.x + a.y * wv.y + a.z * wv.z + a.w * wv.w;
                }
                float nll    = l - emit_z[g];
                float smooth = (float)V_ * l - sz;
                const float eps_i = 0.1f / (float)(V_ - 1);
                atomicAdd(out, (1.0f - 0.1f - eps_i) * nll + eps_i * smooth);
            }
        }
        return;
    }

    const int u = tid;
    const int ua = (u < U1_) ? u : U1_ - 1;

    float val = 0.0f;
    float afin = 0.0f;

    for (int d = 1; d <= (T_ - 1) + (U1_ - 1); d++) {
        int t = d - u;
        // unconditional clamped loads: keep LDS latency off the shfl chain
        int tb = t - 1; tb = tb < 0 ? 0 : (tb > T_ - 1 ? T_ - 1 : tb);
        int tc = t < 0 ? 0 : (t > T_ - 1 ? T_ - 1 : t);
        float blv = blp[tb * U1_ + ua];
        float elv = elp[tc * U1_ + (ua > 0 ? ua - 1 : 0)];
        float up = __shfl_up(val, 1, 64);
        bool valid = (u < U1_) && (t >= 0) && (t < T_);
        if (valid) {
            if (t == 0) {
                val = up + elv;
            } else if (u == 0) {
                val = val + blv;
            } else {
                float a1 = val + blv;
                float a2 = up + elv;
                float mx = fmaxf(a1, a2), mn = fminf(a1, a2);
                val = mx + log1pf(__expf(mn - mx));
            }
            if (t == sl - 1 && u == tl) afin = val;
        }
    }
#pragma unroll
    for (int off = 1; off < 64; off <<= 1) afin += __shfl_xor(afin, off, 64);
    if (u == 0) {
        float bfin = blp[(sl - 1) * U1_ + tl];
        atomicAdd(out, -(afin + bfin));
    }
}

// ---------------------------------------------------------------------------
extern "C" void kernel_launch(void* const* d_in, const int* in_sizes, int n_in,
                              void* d_out, int out_size, void* d_ws, size_t ws_size,
                              hipStream_t stream)
{
    const float* x           = (const float*)d_in[0];
    const float* w           = (const float*)d_in[1];
    const float* bias        = (const float*)d_in[2];
    const int*   targets     = (const int*)d_in[3];
    const int*   src_lengths = (const int*)d_in[4];
    const int*   tgt_lengths = (const int*)d_in[5];
    float* out = (float*)d_out;

    char* p = (char*)d_ws;
    uint8_t* xf8 = (uint8_t*)p;     p += (size_t)M_ * D_;                 // 17.3 MB
    uint8_t* wf8 = (uint8_t*)p;     p += (size_t)V_ * D_;                 //  2.1 MB
    float* se_glob = (float*)p;     p += (size_t)M_ * sizeof(float);      // 135 KB
    float* blank_z = (float*)p;     p += (size_t)M_ * sizeof(float);
    float* emit_z  = (float*)p;     p += (size_t)M_ * sizeof(float);
    float* wsum    = (float*)p;     p += (size_t)(D_ + 4) * sizeof(float);

    hipMemsetAsync(out, 0, sizeof(float), stream);
    hipMemsetAsync(wsum, 0, (D_ + 4) * sizeof(float), stream);
    hipMemsetAsync(se_glob, 0, (size_t)M_ * sizeof(float), stream);

    convert_kernel<<<1536, 256, 0, stream>>>(x, w, bias, xf8, wf8, wsum);
    gemm_fused<<<dim3(M_/TM, V_/TN), 256, 0, stream>>>(xf8, wf8, bias, targets,
                                                       se_glob, blank_z, emit_z);
    dp_kernel<<<B_, 256, 0, stream>>>(se_glob, blank_z, emit_z, targets,
                                      src_lengths, tgt_lengths, x, wsum, out);
}

// Round 6
// 366.868 us; speedup vs baseline: 1.2063x; 1.2063x over previous
//
#include <hip/hip_runtime.h>
#include <hip/hip_bf16.h>
#include <math.h>
#include <stdint.h>

#define B_ 8
#define T_ 128
#define U1_ 33
#define D_ 512
#define V_ 4096
#define M_ (B_*T_*U1_)   /* 33792 */

#define BLANK_ 0
#define PAD_ 1

#define TM 128           /* block M tile */
#define TN 128           /* block N tile */
#define BKB 128          /* K step in fp8 bytes (= MFMA K) */
#define NK (D_/BKB)      /* 4 */
#define GN (V_/TN)       /* 32 n-tiles */

typedef __attribute__((ext_vector_type(4))) float fvec4;
typedef __attribute__((ext_vector_type(8))) int   i8v;    // 32 fp8 = 8 VGPRs
typedef __attribute__((ext_vector_type(4))) int   i4v;

// E8M0 block scales: A x1 (2^0=bias127), B x2^-6 (121) to undo the x64 pre-scale
#define SCALE_A 0x7F7F7F7Fu
#define SCALE_B 0x79797979u

__device__ __forceinline__ void load_lds16(const uint8_t* g, uint8_t* l) {
    __builtin_amdgcn_global_load_lds(
        (const __attribute__((address_space(1))) unsigned int*)g,
        (__attribute__((address_space(3))) unsigned int*)l, 16, 0, 0);
}

__device__ __forceinline__ unsigned pack4_fp8(fvec4 v) {
    int r = __builtin_amdgcn_cvt_pk_fp8_f32(v.x, v.y, 0, false);
    r = __builtin_amdgcn_cvt_pk_fp8_f32(v.z, v.w, r, true);
    return (unsigned)r;
}

// ---------------------------------------------------------------------------
// Kernel 0: fp32 -> fp8 e4m3 convert; w is pre-scaled by 64 (undone by SCALE_B).
// Fused: blocks 0-31 also compute the column-sum of W + bias_sum into wsum
// (sum_v z[r,v] = x_row . wsum + bias_sum is linear -> no sum(z) reduction
// anywhere in the GEMM).  [verified r4/r5, absmax 0]
// ---------------------------------------------------------------------------
__global__ void convert_kernel(const float* __restrict__ x, const float* __restrict__ w,
                               const float* __restrict__ bias,
                               uint8_t* __restrict__ xf8, uint8_t* __restrict__ wf8,
                               float* __restrict__ wsum)
{
    int i = blockIdx.x * 256 + threadIdx.x;
    int stride = gridDim.x * 256;
    const int nx = (M_ * D_) / 16;   // 1081344 16B-groups
    const int nw = (V_ * D_) / 16;   // 131072
    for (int j = i; j < nx; j += stride) {
        const fvec4* p = (const fvec4*)x + (size_t)j * 4;
        uint4 o = { pack4_fp8(p[0]), pack4_fp8(p[1]), pack4_fp8(p[2]), pack4_fp8(p[3]) };
        ((uint4*)xf8)[j] = o;
    }
    for (int j = i; j < nw; j += stride) {
        const fvec4* p = (const fvec4*)w + (size_t)j * 4;
        fvec4 v0 = p[0]*64.0f, v1 = p[1]*64.0f, v2 = p[2]*64.0f, v3 = p[3]*64.0f;
        uint4 o = { pack4_fp8(v0), pack4_fp8(v1), pack4_fp8(v2), pack4_fp8(v3) };
        ((uint4*)wf8)[j] = o;
    }
    // fused wsum: 32 blocks x 256 threads
    if (blockIdx.x < 32) {
        const int t = threadIdx.x;
        const int v0 = blockIdx.x * 128;
        float s0 = 0.0f, s1 = 0.0f;
        for (int v = 0; v < 128; v++) {
            s0 += w[(size_t)(v0 + v) * D_ + t];
            s1 += w[(size_t)(v0 + v) * D_ + t + 256];
        }
        atomicAdd(&wsum[t], s0);
        atomicAdd(&wsum[t + 256], s1);
        if (blockIdx.x == 0) {
            float bsum = 0.0f;
            for (int v = t; v < V_; v += 256) bsum += bias[v];
            atomicAdd(&wsum[D_], bsum);   // bias_sum in slot 512
        }
    }
}

// ---------------------------------------------------------------------------
// Kernel 1: MX-fp8 GEMM — BYTE-IDENTICAL to round-4's verified build
// (174 us, VGPR=96, FETCH 16.8 MB, WRITE 4.5 MB). The K-loop allocation is
// knife-edge fragile (r1/r2/r3/r5 all spilled on small perturbations) —
// DO NOT move code across the loop boundary.
// grid (264, 32), block 256 (2x2 waves of 64x64).
// ---------------------------------------------------------------------------
__global__ __launch_bounds__(256, 2)
void gemm_fused(const uint8_t* __restrict__ xf8, const uint8_t* __restrict__ wf8,
                const float* __restrict__ bias, const int* __restrict__ targets,
                float* __restrict__ partial_e,
                float* __restrict__ blank_z, float* __restrict__ emit_z)
{
    __shared__ __align__(16) uint8_t As[2][TM * BKB];   // 16 KB x2
    __shared__ __align__(16) uint8_t Bs[2][TN * BKB];   // 16 KB x2
    __shared__ float ps[TM];
    __shared__ int tgt_s[TM];

    const int tid  = threadIdx.x;
    const int lane = tid & 63;
    const int wid  = tid >> 6;

    // XCD-chunked swizzle (8448 blocks, 8448%8==0 -> bijective):
    // fid%8 = XCD; XCD k gets m-tiles [33k, 33k+33), n-tile fastest.
    const int fid = blockIdx.y * gridDim.x + blockIdx.x;
    const int xcd = fid & 7;
    const int idx = fid >> 3;            // 0..1055
    const int mt  = xcd * 33 + (idx >> 5);
    const int nt  = idx & 31;
    const int m0  = mt * TM;
    const int n0  = nt * TN;

    // staging: lane i -> LDS (row = wid*32 + j*8 + (i>>3), chunk = i&7);
    // global src chunk is XOR-swizzled by row&7
    const int srow = wid * 32 + (lane >> 3);
    const int schk = (lane & 7) ^ ((lane >> 3) & 7);
    const uint8_t* agp = xf8 + (size_t)(m0 + srow) * D_ + schk * 16;
    const uint8_t* bgp = wf8 + (size_t)(n0 + srow) * D_ + schk * 16;

    fvec4 acc[4][4];
#pragma unroll
    for (int i = 0; i < 4; i++)
#pragma unroll
        for (int j = 0; j < 4; j++) acc[i][j] = (fvec4)0.0f;

    const int wrow = (wid >> 1) * 64;
    const int wcol = (wid & 1) * 64;
    const int m15  = lane & 15;
    const int quad = lane >> 4;

    auto stage = [&](int buf, int ks) {
        const uint8_t* ag = agp + ks * BKB;
        const uint8_t* bg = bgp + ks * BKB;
#pragma unroll
        for (int j = 0; j < 4; j++) {
            load_lds16(ag + j * 8 * D_, &As[buf][(wid * 32 + j * 8) * BKB]);
            load_lds16(bg + j * 8 * D_, &Bs[buf][(wid * 32 + j * 8) * BKB]);
        }
    };

    stage(0, 0);
    __syncthreads();

    const int e   = m15 & 7;               // row&7 for all frag rows
    const int c0b = (((quad << 1) ^ e) << 4);   // first 16B chunk byte offset

    for (int ks = 0; ks < NK; ks++) {
        const int cur = ks & 1;
        if (ks + 1 < NK) stage(cur ^ 1, ks + 1);

        i8v fa[4], fb[4];
#pragma unroll
        for (int mi = 0; mi < 4; mi++) {
            int base = (wrow + mi * 16 + m15) << 7;   // row*128
            union { i4v h[2]; i8v w; } u;
            u.h[0] = *(const i4v*)&As[cur][base + c0b];
            u.h[1] = *(const i4v*)&As[cur][base + (c0b ^ 16)];
            fa[mi] = u.w;
        }
#pragma unroll
        for (int ni = 0; ni < 4; ni++) {
            int base = (wcol + ni * 16 + m15) << 7;
            union { i4v h[2]; i8v w; } u;
            u.h[0] = *(const i4v*)&Bs[cur][base + c0b];
            u.h[1] = *(const i4v*)&Bs[cur][base + (c0b ^ 16)];
            fb[ni] = u.w;
        }
#pragma unroll
        for (int mi = 0; mi < 4; mi++)
#pragma unroll
            for (int ni = 0; ni < 4; ni++)
                acc[mi][ni] = __builtin_amdgcn_mfma_scale_f32_16x16x128_f8f6f4(
                                  fa[mi], fb[ni], acc[mi][ni],
                                  0, 0,                 // fmtA=fp8, fmtB=fp8
                                  0, SCALE_A, 0, SCALE_B);
        __syncthreads();
    }

    // ---- epilogue ----
    if (tid < TM) {
        ps[tid] = 0.0f;
        int row = m0 + tid;
        int u = row % U1_;
        int b = row / (T_ * U1_);
        tgt_s[tid] = (u < U1_ - 1) ? targets[b * (U1_ - 1) + u] : -1;
    }
    __syncthreads();

    float bv[4];
#pragma unroll
    for (int ni = 0; ni < 4; ni++) bv[ni] = bias[n0 + wcol + ni * 16 + m15];

    const bool blank_lane = (nt == 0) && (wcol == 0) && (m15 == 0);

#pragma unroll
    for (int mi = 0; mi < 4; mi++) {
#pragma unroll
        for (int r = 0; r < 4; r++) {
            const int irow = wrow + mi * 16 + quad * 4 + r;
            float se = 0.0f;
#pragma unroll
            for (int ni = 0; ni < 4; ni++) {
                float z = acc[mi][ni][r] + bv[ni];
                se += __expf(z);
                int c = n0 + wcol + ni * 16 + m15;
                if (tgt_s[irow] == c) emit_z[m0 + irow] = z;
            }
            if (blank_lane) blank_z[m0 + irow] = acc[mi][0][r] + bv[0];
            se += __shfl_xor(se, 1, 64);
            se += __shfl_xor(se, 2, 64);
            se += __shfl_xor(se, 4, 64);
            se += __shfl_xor(se, 8, 64);
            if (m15 == 0) atomicAdd(&ps[irow], se);
        }
    }
    __syncthreads();
    if (tid < TM) {
        partial_e[(size_t)nt * M_ + m0 + tid] = ps[tid];
    }
}

// ---------------------------------------------------------------------------
// Kernel 2: combine partials -> lse; fused label-smoothed CE contribution.
// Wide (132 blocks): the 32-way combine reads are coalesced per j-slice.
// sum(z) for CE rows computed analytically: x_row . wsum + bias_sum (fp32).
// [verified r3, absmax 0]
// ---------------------------------------------------------------------------
__global__ void lse_combine(const float* __restrict__ partial_e,
                            const float* __restrict__ emit_z, const int* __restrict__ targets,
                            const int* __restrict__ src_lengths,
                            const float* __restrict__ x, const float* __restrict__ wsum,
                            float* __restrict__ lse, float* __restrict__ out)
{
    int r = blockIdx.x * 256 + threadIdx.x;   // grid covers M_ exactly
    float se = 0.0f;
#pragma unroll
    for (int j = 0; j < GN; j++) se += partial_e[(size_t)j * M_ + r];
    float l = __logf(se);
    lse[r] = l;

    // CE: rows with t == src_len-1, u < U1-1, target != PAD
    int b   = r / (T_ * U1_);
    int rem = r % (T_ * U1_);
    int t   = rem / U1_;
    int u   = rem % U1_;
    if (u < U1_ - 1 && t == src_lengths[b] - 1) {
        int tgt = targets[b * (U1_ - 1) + u];
        if (tgt != PAD_) {
            // sum_v z = x_row . wsum + bias_sum  (exact fp32)
            float sz = wsum[D_];
            const fvec4* xr = (const fvec4*)(x + (size_t)r * D_);
            const fvec4* ws = (const fvec4*)wsum;
#pragma unroll 4
            for (int d = 0; d < D_ / 4; d++) {
                fvec4 a = xr[d], wv = ws[d];
                sz += a.x * wv.x + a.y * wv.y + a.z * wv.z + a.w * wv.w;
            }
            float nll    = l - emit_z[r];
            float smooth = (float)V_ * l - sz;
            const float eps_i = 0.1f / (float)(V_ - 1);
            atomicAdd(out, (1.0f - 0.1f - eps_i) * nll + eps_i * smooth);
        }
    }
}

// ---------------------------------------------------------------------------
// Kernel 3: RNN-T forward DP from LDS, one block per utterance
// [verified r0, absmax 0]
// ---------------------------------------------------------------------------
__global__ __launch_bounds__(256)
void dp_kernel(const float* __restrict__ blank_z, const float* __restrict__ emit_z,
               const float* __restrict__ lse, const int* __restrict__ src_lengths,
               const int* __restrict__ tgt_lengths, float* __restrict__ out)
{
    __shared__ float blp[T_ * U1_];
    __shared__ float elp[T_ * U1_];
    const int tid = threadIdx.x;
    const int b = blockIdx.x;
    for (int i = tid; i < T_ * U1_; i += 256) {
        int g = b * T_ * U1_ + i;
        float l = lse[g];
        blp[i] = blank_z[g] - l;
        elp[i] = emit_z[g] - l;
    }
    __syncthreads();
    if (tid >= 64) return;

    const int u = tid;
    const int ua = (u < U1_) ? u : U1_ - 1;
    const int sl = src_lengths[b], tl = tgt_lengths[b];

    float val = 0.0f;
    float afin = 0.0f;

    for (int d = 1; d <= (T_ - 1) + (U1_ - 1); d++) {
        int t = d - u;
        // unconditional clamped loads: keep LDS latency off the shfl chain
        int tb = t - 1; tb = tb < 0 ? 0 : (tb > T_ - 1 ? T_ - 1 : tb);
        int tc = t < 0 ? 0 : (t > T_ - 1 ? T_ - 1 : t);
        float blv = blp[tb * U1_ + ua];
        float elv = elp[tc * U1_ + (ua > 0 ? ua - 1 : 0)];
        float up = __shfl_up(val, 1, 64);
        bool valid = (u < U1_) && (t >= 0) && (t < T_);
        if (valid) {
            if (t == 0) {
                val = up + elv;
            } else if (u == 0) {
                val = val + blv;
            } else {
                float a1 = val + blv;
                float a2 = up + elv;
                float mx = fmaxf(a1, a2), mn = fminf(a1, a2);
                val = mx + log1pf(__expf(mn - mx));
            }
            if (t == sl - 1 && u == tl) afin = val;
        }
    }
#pragma unroll
    for (int off = 1; off < 64; off <<= 1) afin += __shfl_xor(afin, off, 64);
    if (u == 0) {
        float bfin = blp[(sl - 1) * U1_ + tl];
        atomicAdd(out, -(afin + bfin));
    }
}

// ---------------------------------------------------------------------------
extern "C" void kernel_launch(void* const* d_in, const int* in_sizes, int n_in,
                              void* d_out, int out_size, void* d_ws, size_t ws_size,
                              hipStream_t stream)
{
    const float* x           = (const float*)d_in[0];
    const float* w           = (const float*)d_in[1];
    const float* bias        = (const float*)d_in[2];
    const int*   targets     = (const int*)d_in[3];
    const int*   src_lengths = (const int*)d_in[4];
    const int*   tgt_lengths = (const int*)d_in[5];
    float* out = (float*)d_out;

    char* p = (char*)d_ws;
    uint8_t* xf8 = (uint8_t*)p;     p += (size_t)M_ * D_;                 // 17.3 MB
    uint8_t* wf8 = (uint8_t*)p;     p += (size_t)V_ * D_;                 //  2.1 MB
    float* partial_e = (float*)p;   p += (size_t)GN * M_ * sizeof(float); //  4.3 MB
    float* lse       = (float*)p;   p += (size_t)M_ * sizeof(float);
    float* blank_z   = (float*)p;   p += (size_t)M_ * sizeof(float);
    float* emit_z    = (float*)p;   p += (size_t)M_ * sizeof(float);
    float* wsum      = (float*)p;   p += (size_t)(D_ + 4) * sizeof(float);

    hipMemsetAsync(out, 0, sizeof(float), stream);
    hipMemsetAsync(wsum, 0, (D_ + 4) * sizeof(float), stream);

    convert_kernel<<<1536, 256, 0, stream>>>(x, w, bias, xf8, wf8, wsum);
    gemm_fused<<<dim3(M_/TM, V_/TN), 256, 0, stream>>>(xf8, wf8, bias, targets,
                                                       partial_e, blank_z, emit_z);
    lse_combine<<<M_/256, 256, 0, stream>>>(partial_e, emit_z, targets,
                                            src_lengths, x, wsum, lse, out);
    dp_kernel<<<B_, 256, 0, stream>>>(blank_z, emit_z, lse, src_lengths, tgt_lengths, out);
}